// Round 4
// baseline (279.629 us; speedup 1.0000x reference)
//
#include <hip/hip_runtime.h>
#include <hip/hip_cooperative_groups.h>

namespace cg = cooperative_groups;

#define N_TOK 8192

typedef _Float16 f16x8 __attribute__((ext_vector_type(8)));
typedef _Float16 f16x4 __attribute__((ext_vector_type(4)));
typedef float    f32x4 __attribute__((ext_vector_type(4)));

__device__ __forceinline__ f32x4 mfma_k32(f16x8 a, f16x8 b, f32x4 c) {
  return __builtin_amdgcn_mfma_f32_16x16x32_f16(a, b, c, 0, 0, 0);
}
// Legacy K=16 MFMA: B-frag layout B[k=quad*4+b][col=l15] matches the K=32
// C layout (rows quad*4+r in regs) exactly -> P feeds PV with NO transpose.
__device__ __forceinline__ f32x4 mfma_k16(f16x4 a, f16x4 b, f32x4 c) {
  return __builtin_amdgcn_mfma_f32_16x16x16f16(a, b, c, 0, 0, 0);
}

// QSCALE^2 = log2(e)/sqrt(32); fold softmax scale + ln->log2 into q so
// s2[n,m] = qe_n . qe_m is directly the exp2 exponent.
#define QSCALE 0.50500977f

// ---------------------------------------------------------------------------
// Fully fused cooperative kernel: 256 blocks x 1024 threads (1 block/CU).
// Phase 1: per-block n-slice prep (qe slice + blocked vht slice), dense loads.
// Phase 2: Bn[n] = log2(sum_m exp2(qe_n.qe_m))  (rows n0..n0+31 per block)
// Phase 3: out[c,m] = sum_n vh[c,n]*exp2(qe_n.qe_m - Bn[n]) + x   (32 m/block)
// grid.sync() between phases (device-scope fence for cross-XCD visibility).
// ---------------------------------------------------------------------------
__global__ __launch_bounds__(1024) void fused_kernel(
    const float* __restrict__ x, const float* __restrict__ W,
    const float* __restrict__ bias, _Float16* __restrict__ qe,
    _Float16* __restrict__ vht, float* __restrict__ Bn,
    float* __restrict__ out) {
  __shared__ union {
    struct {
      float Wl[32 * 65];  // pad 65: conflict-free column reads
      float xl[64 * 36];  // pad 36: 16B-aligned rows, broadcast reads
    } p1;
    float Lp[16][32];     // phase 2 partials
    float Ot[8 * 64 * 33];// phase 3 combine
  } sm;

  cg::grid_group grid = cg::this_grid();
  int t = threadIdx.x;
  int b = blockIdx.x;
  int n0 = b * 32;  // this block's n-slice (phases 1-2) and m-tile (phase 3)
  int w = t >> 6, lane = t & 63, quad = lane >> 4, l15 = lane & 15;

  // ------------------------------------------------------------ Phase 1
  // W -> LDS (row-major, stride 65)
  for (int i = t; i < 2048; i += 1024)
    sm.p1.Wl[(i >> 6) * 65 + (i & 63)] = W[i];
  // x-slice [64 c][32 n] -> LDS (dense f32x4: 8 threads cover one full
  // 128B line per channel row) + emit the vht blocked slice.
  if (t < 512) {
    int c = t >> 3, j4 = t & 7;  // j4 = n_local/4
    f32x4 v = *(const f32x4*)(x + c * N_TOK + n0 + j4 * 4);
    *(f32x4*)&sm.p1.xl[c * 36 + j4 * 4] = v;
    f16x4 hv;
#pragma unroll
    for (int j = 0; j < 4; ++j) hv[j] = (_Float16)v[j];
    int q = j4 & 3, h = j4 >> 2;  // inner order: pos = q*8 + h*4 (+r)
    *(f16x4*)(vht + b * 2048 + c * 32 + q * 8 + h * 4) = hv;
  }
  __syncthreads();
  {  // qe[n0+nl][o] = fp16((W x + bias) * QSCALE), 2-chain ILP
    int nl = t >> 5, o = t & 31;
    float a0 = bias[o], a1 = 0.f;
#pragma unroll
    for (int c = 0; c < 32; ++c) {
      a0 = fmaf(sm.p1.Wl[o * 65 + c], sm.p1.xl[c * 36 + nl], a0);
      a1 = fmaf(sm.p1.Wl[o * 65 + 32 + c], sm.p1.xl[(32 + c) * 36 + nl], a1);
    }
    qe[(n0 + nl) * 32 + o] = (_Float16)((a0 + a1) * QSCALE);
  }
  __threadfence();
  grid.sync();

  // ------------------------------------------------------------ Phase 2
  {
    f16x8 af0 = *(const f16x8*)(qe + (n0 + l15) * 32 + quad * 8);
    f16x8 af1 = *(const f16x8*)(qe + (n0 + 16 + l15) * 32 + quad * 8);
    f32x4 sums0 = {0.f, 0.f, 0.f, 0.f}, sums1 = {0.f, 0.f, 0.f, 0.f};
    for (int mt = 0; mt < 16; ++mt) {
      int m0 = w * 512 + mt * 32;
      f16x8 bf0 = *(const f16x8*)(qe + (m0 + l15) * 32 + quad * 8);
      f16x8 bf1 = *(const f16x8*)(qe + (m0 + 16 + l15) * 32 + quad * 8);
      f32x4 zero = {0.f, 0.f, 0.f, 0.f};
      f32x4 s00 = mfma_k32(af0, bf0, zero);
      f32x4 s01 = mfma_k32(af0, bf1, zero);
      f32x4 s10 = mfma_k32(af1, bf0, zero);
      f32x4 s11 = mfma_k32(af1, bf1, zero);
#pragma unroll
      for (int r = 0; r < 4; ++r) {
        sums0[r] +=
            __builtin_amdgcn_exp2f(s00[r]) + __builtin_amdgcn_exp2f(s01[r]);
        sums1[r] +=
            __builtin_amdgcn_exp2f(s10[r]) + __builtin_amdgcn_exp2f(s11[r]);
      }
    }
#pragma unroll
    for (int r = 0; r < 4; ++r) {
#pragma unroll
      for (int mask = 1; mask < 16; mask <<= 1) {
        sums0[r] += __shfl_xor(sums0[r], mask, 64);
        sums1[r] += __shfl_xor(sums1[r], mask, 64);
      }
    }
    if (l15 == 0) {
      *(f32x4*)&sm.Lp[w][quad * 4] = sums0;
      *(f32x4*)&sm.Lp[w][16 + quad * 4] = sums1;
    }
    __syncthreads();
    if (t < 32) {
      float L = 0.f;
#pragma unroll
      for (int ww = 0; ww < 16; ++ww) L += sm.Lp[ww][t];
      Bn[n0 + t] = __builtin_amdgcn_logf(L);  // v_log_f32 = log2
    }
  }
  __threadfence();
  grid.sync();

  // ------------------------------------------------------------ Phase 3
  {
    int m0 = n0;  // this block's 32 m-columns
    f16x8 bm0 = *(const f16x8*)(qe + (m0 + l15) * 32 + quad * 8);
    f16x8 bm1 = *(const f16x8*)(qe + (m0 + 16 + l15) * 32 + quad * 8);

    f32x4 acc[4][2];
#pragma unroll
    for (int ct = 0; ct < 4; ++ct)
#pragma unroll
      for (int mt = 0; mt < 2; ++mt) acc[ct][mt] = f32x4{0.f, 0.f, 0.f, 0.f};

    // Double-buffered chunk operands (register sets A/B, static names).
    f16x8 anA0, anA1, avA[4];
    f32x4 BqA0, BqA1;
    f16x8 anB0, anB1, avB[4];
    f32x4 BqB0, BqB1;

#define LOADCH(SUF, NB)                                                    \
  do {                                                                     \
    int nb_ = (NB);                                                        \
    an##SUF##0 = *(const f16x8*)(qe + (nb_ + l15) * 32 + quad * 8);        \
    an##SUF##1 = *(const f16x8*)(qe + (nb_ + 16 + l15) * 32 + quad * 8);   \
    Bq##SUF##0 = *(const f32x4*)(Bn + nb_ + quad * 4);                     \
    Bq##SUF##1 = *(const f32x4*)(Bn + nb_ + 16 + quad * 4);                \
    const _Float16* vb_ = vht + (nb_ >> 5) * 2048 + l15 * 32 + quad * 8;   \
    _Pragma("unroll") for (int ct = 0; ct < 4; ++ct) av##SUF[ct] =         \
        *(const f16x8*)(vb_ + ct * 512);                                   \
  } while (0)

#define COMPUTECH(SUF)                                                     \
  do {                                                                     \
    f32x4 zero = {0.f, 0.f, 0.f, 0.f};                                     \
    f32x4 s00 = mfma_k32(an##SUF##0, bm0, zero);                           \
    f32x4 s01 = mfma_k32(an##SUF##0, bm1, zero);                           \
    f32x4 s10 = mfma_k32(an##SUF##1, bm0, zero);                           \
    f32x4 s11 = mfma_k32(an##SUF##1, bm1, zero);                           \
    f16x4 p00, p01, p10, p11;                                              \
    _Pragma("unroll") for (int r = 0; r < 4; ++r) {                        \
      p00[r] = (_Float16)__builtin_amdgcn_exp2f(s00[r] - Bq##SUF##0[r]);   \
      p01[r] = (_Float16)__builtin_amdgcn_exp2f(s01[r] - Bq##SUF##0[r]);   \
      p10[r] = (_Float16)__builtin_amdgcn_exp2f(s10[r] - Bq##SUF##1[r]);   \
      p11[r] = (_Float16)__builtin_amdgcn_exp2f(s11[r] - Bq##SUF##1[r]);   \
    }                                                                      \
    _Pragma("unroll") for (int ct = 0; ct < 4; ++ct) {                     \
      f16x4 lo, hi;                                                        \
      _Pragma("unroll") for (int j = 0; j < 4; ++j) {                      \
        lo[j] = av##SUF[ct][j];                                            \
        hi[j] = av##SUF[ct][j + 4];                                        \
      }                                                                    \
      acc[ct][0] = mfma_k16(lo, p00, acc[ct][0]);                          \
      acc[ct][0] = mfma_k16(hi, p10, acc[ct][0]);                          \
      acc[ct][1] = mfma_k16(lo, p01, acc[ct][1]);                          \
      acc[ct][1] = mfma_k16(hi, p11, acc[ct][1]);                          \
    }                                                                      \
  } while (0)

    int nbase = w * 512;
    LOADCH(A, nbase);
    for (int ch2 = 0; ch2 < 8; ++ch2) {
      int nb = nbase + ch2 * 64;
      LOADCH(B, nb + 32);
      COMPUTECH(A);
      if (ch2 < 7) LOADCH(A, nb + 64);
      COMPUTECH(B);
    }
#undef LOADCH
#undef COMPUTECH

    // Combine partials across the 16 n-segments (staged: 16 -> 8 -> 1).
    __syncthreads();  // Lp reads (phase 2) long done; reuse as Ot
    if (w < 8) {
#pragma unroll
      for (int ct = 0; ct < 4; ++ct)
#pragma unroll
        for (int mt = 0; mt < 2; ++mt)
#pragma unroll
          for (int r = 0; r < 4; ++r)
            sm.Ot[(w * 64 + ct * 16 + quad * 4 + r) * 33 + mt * 16 + l15] =
                acc[ct][mt][r];
    }
    __syncthreads();
    if (w >= 8) {
#pragma unroll
      for (int ct = 0; ct < 4; ++ct)
#pragma unroll
        for (int mt = 0; mt < 2; ++mt)
#pragma unroll
          for (int r = 0; r < 4; ++r)
            sm.Ot[((w - 8) * 64 + ct * 16 + quad * 4 + r) * 33 + mt * 16 +
                  l15] += acc[ct][mt][r];
    }
    __syncthreads();
    // 2048 outputs, 1024 threads -> 2 each; m consecutive across lanes.
    for (int idx = t; idx < 2048; idx += 1024) {
      int cc = idx >> 5, m = idx & 31;
      float v = 0.f;
#pragma unroll
      for (int s = 0; s < 8; ++s) v += sm.Ot[(s * 64 + cc) * 33 + m];
      out[cc * N_TOK + m0 + m] = v + x[cc * N_TOK + m0 + m];
    }
  }
}

// ---------------------------------------------------------------------------
extern "C" void kernel_launch(void* const* d_in, const int* in_sizes, int n_in,
                              void* d_out, int out_size, void* d_ws,
                              size_t ws_size, hipStream_t stream) {
  const float* x = (const float*)d_in[0];     // [64][8192]
  const float* W = (const float*)d_in[1];     // [32][64]
  const float* bias = (const float*)d_in[2];  // [32]
  float* out = (float*)d_out;                 // [64][8192]

  char* ws = (char*)d_ws;
  _Float16* qe = (_Float16*)ws;                 // 8192*32*2 = 512 KB
  _Float16* vht = (_Float16*)(ws + 524288);     // blocked vh: 1 MB
  float* Bn = (float*)(ws + 524288 + 1048576);  // 8192*4 = 32 KB

  void* args[] = {(void*)&x,   (void*)&W,  (void*)&bias, (void*)&qe,
                  (void*)&vht, (void*)&Bn, (void*)&out};
  hipLaunchCooperativeKernel((const void*)fused_kernel, dim3(256), dim3(1024),
                             args, 0, stream);
}

// Round 5
// 119.435 us; speedup vs baseline: 2.3413x; 2.3413x over previous
//
#include <hip/hip_runtime.h>

#define N_TOK 8192

typedef _Float16 f16x8 __attribute__((ext_vector_type(8)));
typedef _Float16 f16x4 __attribute__((ext_vector_type(4)));
typedef float    f32x4 __attribute__((ext_vector_type(4)));

__device__ __forceinline__ f32x4 mfma_k32(f16x8 a, f16x8 b, f32x4 c) {
  return __builtin_amdgcn_mfma_f32_16x16x32_f16(a, b, c, 0, 0, 0);
}
// Legacy K=16 MFMA: B-frag layout B[k=quad*4+b][col=l15] matches the K=32
// C layout (rows quad*4+r in regs) exactly -> P feeds PV with NO transpose.
__device__ __forceinline__ f32x4 mfma_k16(f16x4 a, f16x4 b, f32x4 c) {
  return __builtin_amdgcn_mfma_f32_16x16x16f16(a, b, c, 0, 0, 0);
}

// QSCALE^2 = log2(e)/sqrt(32); fold softmax scale + ln->log2 into q so
// s2[n,m] = qe_n . qe_m is directly the exp2 exponent.
#define QSCALE 0.50500977f

// ---------------------------------------------------------------------------
// Kernel A (prep): 256 blocks x 1024 thr; block b owns n-slice n0=b*32.
// Dense f32x4 x loads (full 128B lines) staged in LDS; emits qe slice and
// blocked vht slice. vht[nblk][c][inner32]: inner pos = q*8 + h*4 (+r) for
// n_local = (h*4+q)*4+r -- a lane's f16x8 at inner q*8 holds n_local
// {q*4..+3, 16+q*4..+3} = the two K=16 PV A-frags.
// ---------------------------------------------------------------------------
__global__ __launch_bounds__(1024) void prep_kernel(
    const float* __restrict__ x, const float* __restrict__ W,
    const float* __restrict__ bias, _Float16* __restrict__ qe,
    _Float16* __restrict__ vht) {
  __shared__ float Wl[32 * 65];
  __shared__ float xl[64 * 36];
  int t = threadIdx.x, b = blockIdx.x;
  int n0 = b * 32;
  for (int i = t; i < 2048; i += 1024)
    Wl[(i >> 6) * 65 + (i & 63)] = W[i];
  if (t < 512) {
    int c = t >> 3, j4 = t & 7;  // j4 = n_local/4
    f32x4 v = *(const f32x4*)(x + c * N_TOK + n0 + j4 * 4);
    *(f32x4*)&xl[c * 36 + j4 * 4] = v;
    f16x4 hv;
#pragma unroll
    for (int j = 0; j < 4; ++j) hv[j] = (_Float16)v[j];
    int q = j4 & 3, h = j4 >> 2;
    *(f16x4*)(vht + b * 2048 + c * 32 + q * 8 + h * 4) = hv;
  }
  __syncthreads();
  int nl = t >> 5, o = t & 31;
  float a0 = bias[o], a1 = 0.f;
#pragma unroll
  for (int c = 0; c < 32; ++c) {
    a0 = fmaf(Wl[o * 65 + c], xl[c * 36 + nl], a0);
    a1 = fmaf(Wl[o * 65 + 32 + c], xl[(32 + c) * 36 + nl], a1);
  }
  qe[(n0 + nl) * 32 + o] = (_Float16)((a0 + a1) * QSCALE);
}

// ---------------------------------------------------------------------------
// Kernel B (pass 1): Bn[n] = log2( sum_m exp2(qe_n . qe_m) )
// 256 blocks x 1024 thr (16 waves): block = 32 rows, waves split 8192 m
// 16 ways. Explicit A/B double-buffered bf prefetch; launch_bounds(1024,4)
// gives the allocator a 128-VGPR budget so both buffers stay live.
// ---------------------------------------------------------------------------
__global__ __launch_bounds__(1024, 4) void pass1_kernel(
    const _Float16* __restrict__ qe, float* __restrict__ Bn) {
  __shared__ float Lp[16][32];
  int t = threadIdx.x;
  int w = t >> 6, lane = t & 63, quad = lane >> 4, l15 = lane & 15;
  int n0 = blockIdx.x * 32;
  f16x8 af0 = *(const f16x8*)(qe + (n0 + l15) * 32 + quad * 8);
  f16x8 af1 = *(const f16x8*)(qe + (n0 + 16 + l15) * 32 + quad * 8);
  f32x4 sums0 = {0.f, 0.f, 0.f, 0.f}, sums1 = {0.f, 0.f, 0.f, 0.f};
  int mbase = w * 512;
  f16x8 bfA0, bfA1, bfB0, bfB1;
  bfA0 = *(const f16x8*)(qe + (mbase + l15) * 32 + quad * 8);
  bfA1 = *(const f16x8*)(qe + (mbase + 16 + l15) * 32 + quad * 8);

#define P1_STEP(BF0, BF1)                                                   \
  do {                                                                      \
    f32x4 zero = {0.f, 0.f, 0.f, 0.f};                                      \
    f32x4 s00 = mfma_k32(af0, BF0, zero);                                   \
    f32x4 s01 = mfma_k32(af0, BF1, zero);                                   \
    f32x4 s10 = mfma_k32(af1, BF0, zero);                                   \
    f32x4 s11 = mfma_k32(af1, BF1, zero);                                   \
    _Pragma("unroll") for (int r = 0; r < 4; ++r) {                         \
      sums0[r] +=                                                           \
          __builtin_amdgcn_exp2f(s00[r]) + __builtin_amdgcn_exp2f(s01[r]);  \
      sums1[r] +=                                                           \
          __builtin_amdgcn_exp2f(s10[r]) + __builtin_amdgcn_exp2f(s11[r]);  \
    }                                                                       \
  } while (0)

  for (int mt2 = 0; mt2 < 8; ++mt2) {
    int m0 = mbase + mt2 * 64;
    bfB0 = *(const f16x8*)(qe + (m0 + 32 + l15) * 32 + quad * 8);
    bfB1 = *(const f16x8*)(qe + (m0 + 48 + l15) * 32 + quad * 8);
    P1_STEP(bfA0, bfA1);
    if (mt2 < 7) {
      bfA0 = *(const f16x8*)(qe + (m0 + 64 + l15) * 32 + quad * 8);
      bfA1 = *(const f16x8*)(qe + (m0 + 80 + l15) * 32 + quad * 8);
    }
    P1_STEP(bfB0, bfB1);
  }
#undef P1_STEP

#pragma unroll
  for (int r = 0; r < 4; ++r) {
#pragma unroll
    for (int mask = 1; mask < 16; mask <<= 1) {
      sums0[r] += __shfl_xor(sums0[r], mask, 64);
      sums1[r] += __shfl_xor(sums1[r], mask, 64);
    }
  }
  if (l15 == 0) {
    *(f32x4*)&Lp[w][quad * 4] = sums0;
    *(f32x4*)&Lp[w][16 + quad * 4] = sums1;
  }
  __syncthreads();
  if (t < 32) {
    float L = 0.f;
#pragma unroll
    for (int ww = 0; ww < 16; ++ww) L += Lp[ww][t];
    Bn[n0 + t] = __builtin_amdgcn_logf(L);  // v_log_f32 = log2
  }
}

// ---------------------------------------------------------------------------
// Kernel C (pass 2): out[c,m] = sum_n vh[c,n] * exp2(qe_n.qe_m - Bn[n]) + x
// 256 blocks x 1024 thr (16 waves). Block = 32 m-cols, all 64 c.
// Waves split n 16 ways (512 each), chunk = 32 n, A/B double-buffered.
// launch_bounds(1024,4): 128-VGPR budget so both operand sets (104 VGPRs
// live) survive regalloc -- without it hipcc targets 64 VGPR and sinks the
// prefetch loads, destroying the pipeline (round-3 VGPR_Count=60, 37us).
// ---------------------------------------------------------------------------
__global__ __launch_bounds__(1024, 4) void pass2_kernel(
    const _Float16* __restrict__ qe, const _Float16* __restrict__ vht,
    const float* __restrict__ Bn, const float* __restrict__ x,
    float* __restrict__ out) {
  __shared__ float Ot[8 * 64 * 33];  // combine: [8 sets][64 c][33]
  int t = threadIdx.x;
  int w = t >> 6, lane = t & 63, quad = lane >> 4, l15 = lane & 15;
  int m0 = blockIdx.x * 32;

  // B frags for the S matmul: cols m0..m0+31 (fixed for whole kernel)
  f16x8 bm0 = *(const f16x8*)(qe + (m0 + l15) * 32 + quad * 8);
  f16x8 bm1 = *(const f16x8*)(qe + (m0 + 16 + l15) * 32 + quad * 8);

  f32x4 acc[4][2];
#pragma unroll
  for (int ct = 0; ct < 4; ++ct)
#pragma unroll
    for (int mt = 0; mt < 2; ++mt) acc[ct][mt] = f32x4{0.f, 0.f, 0.f, 0.f};

  // Double-buffered chunk operands (register sets A/B, all static names).
  f16x8 anA0, anA1, avA[4];
  f32x4 BqA0, BqA1;
  f16x8 anB0, anB1, avB[4];
  f32x4 BqB0, BqB1;

#define LOADCH(SUF, NB)                                                     \
  do {                                                                      \
    int nb_ = (NB);                                                         \
    an##SUF##0 = *(const f16x8*)(qe + (nb_ + l15) * 32 + quad * 8);         \
    an##SUF##1 = *(const f16x8*)(qe + (nb_ + 16 + l15) * 32 + quad * 8);    \
    Bq##SUF##0 = *(const f32x4*)(Bn + nb_ + quad * 4);                      \
    Bq##SUF##1 = *(const f32x4*)(Bn + nb_ + 16 + quad * 4);                 \
    const _Float16* vb_ = vht + (nb_ >> 5) * 2048 + l15 * 32 + quad * 8;    \
    _Pragma("unroll") for (int ct = 0; ct < 4; ++ct) av##SUF[ct] =          \
        *(const f16x8*)(vb_ + ct * 512);                                    \
  } while (0)

#define COMPUTECH(SUF)                                                      \
  do {                                                                      \
    f32x4 zero = {0.f, 0.f, 0.f, 0.f};                                      \
    f32x4 s00 = mfma_k32(an##SUF##0, bm0, zero); /* n=quad*4+r, m=l15 */    \
    f32x4 s01 = mfma_k32(an##SUF##0, bm1, zero); /* m=16+l15 */             \
    f32x4 s10 = mfma_k32(an##SUF##1, bm0, zero); /* n=16+quad*4+r */        \
    f32x4 s11 = mfma_k32(an##SUF##1, bm1, zero);                            \
    f16x4 p00, p01, p10, p11;                                               \
    _Pragma("unroll") for (int r = 0; r < 4; ++r) {                         \
      p00[r] = (_Float16)__builtin_amdgcn_exp2f(s00[r] - Bq##SUF##0[r]);    \
      p01[r] = (_Float16)__builtin_amdgcn_exp2f(s01[r] - Bq##SUF##0[r]);    \
      p10[r] = (_Float16)__builtin_amdgcn_exp2f(s10[r] - Bq##SUF##1[r]);    \
      p11[r] = (_Float16)__builtin_amdgcn_exp2f(s11[r] - Bq##SUF##1[r]);    \
    }                                                                       \
    _Pragma("unroll") for (int ct = 0; ct < 4; ++ct) {                      \
      f16x4 lo, hi;                                                         \
      _Pragma("unroll") for (int j = 0; j < 4; ++j) {                       \
        lo[j] = av##SUF[ct][j];                                             \
        hi[j] = av##SUF[ct][j + 4];                                         \
      }                                                                     \
      acc[ct][0] = mfma_k16(lo, p00, acc[ct][0]);                           \
      acc[ct][0] = mfma_k16(hi, p10, acc[ct][0]);                           \
      acc[ct][1] = mfma_k16(lo, p01, acc[ct][1]);                           \
      acc[ct][1] = mfma_k16(hi, p11, acc[ct][1]);                           \
    }                                                                       \
  } while (0)

  int nbase = w * 512;
  LOADCH(A, nbase);
  for (int ch2 = 0; ch2 < 8; ++ch2) {
    int nb = nbase + ch2 * 64;
    LOADCH(B, nb + 32);
    COMPUTECH(A);
    if (ch2 < 7) LOADCH(A, nb + 64);
    COMPUTECH(B);
  }
#undef LOADCH
#undef COMPUTECH

  // Combine partials across the 16 n-segments (staged: 16 -> 8 -> 1).
  if (w < 8) {
#pragma unroll
    for (int ct = 0; ct < 4; ++ct)
#pragma unroll
      for (int mt = 0; mt < 2; ++mt)
#pragma unroll
        for (int r = 0; r < 4; ++r)
          Ot[(w * 64 + ct * 16 + quad * 4 + r) * 33 + mt * 16 + l15] =
              acc[ct][mt][r];
  }
  __syncthreads();
  if (w >= 8) {
#pragma unroll
    for (int ct = 0; ct < 4; ++ct)
#pragma unroll
      for (int mt = 0; mt < 2; ++mt)
#pragma unroll
        for (int r = 0; r < 4; ++r)
          Ot[((w - 8) * 64 + ct * 16 + quad * 4 + r) * 33 + mt * 16 + l15] +=
              acc[ct][mt][r];
  }
  __syncthreads();
  // 2048 outputs, 1024 threads -> 2 each; m consecutive across lanes.
  for (int idx = t; idx < 2048; idx += 1024) {
    int cc = idx >> 5, m = idx & 31;
    float v = 0.f;
#pragma unroll
    for (int s = 0; s < 8; ++s) v += Ot[(s * 64 + cc) * 33 + m];
    out[cc * N_TOK + m0 + m] = v + x[cc * N_TOK + m0 + m];
  }
}

// ---------------------------------------------------------------------------
extern "C" void kernel_launch(void* const* d_in, const int* in_sizes, int n_in,
                              void* d_out, int out_size, void* d_ws,
                              size_t ws_size, hipStream_t stream) {
  const float* x = (const float*)d_in[0];     // [64][8192]
  const float* W = (const float*)d_in[1];     // [32][64]
  const float* bias = (const float*)d_in[2];  // [32]
  float* out = (float*)d_out;                 // [64][8192]

  char* ws = (char*)d_ws;
  _Float16* qe = (_Float16*)ws;                 // 8192*32*2 = 512 KB
  _Float16* vht = (_Float16*)(ws + 524288);     // blocked vh: 1 MB
  float* Bn = (float*)(ws + 524288 + 1048576);  // 8192*4 = 32 KB

  prep_kernel<<<256, 1024, 0, stream>>>(x, W, bias, qe, vht);
  pass1_kernel<<<256, 1024, 0, stream>>>(qe, Bn);
  pass2_kernel<<<256, 1024, 0, stream>>>(qe, vht, Bn, x, out);
}

// Round 6
// 99.853 us; speedup vs baseline: 2.8004x; 1.1961x over previous
//
#include <hip/hip_runtime.h>

#define N_TOK 8192

typedef _Float16 f16x8 __attribute__((ext_vector_type(8)));
typedef _Float16 f16x4 __attribute__((ext_vector_type(4)));
typedef float    f32x4 __attribute__((ext_vector_type(4)));

__device__ __forceinline__ f32x4 mfma_k32(f16x8 a, f16x8 b, f32x4 c) {
  return __builtin_amdgcn_mfma_f32_16x16x32_f16(a, b, c, 0, 0, 0);
}
// Legacy K=16 MFMA: B-frag layout B[k=quad*4+b][col=l15] matches the K=32
// C layout (rows quad*4+r in regs) exactly -> P feeds PV with NO transpose.
__device__ __forceinline__ f32x4 mfma_k16(f16x4 a, f16x4 b, f32x4 c) {
  return __builtin_amdgcn_mfma_f32_16x16x16f16(a, b, c, 0, 0, 0);
}

// QSCALE^2 = log2(e)/sqrt(32); fold softmax scale + ln->log2 into q so
// s2[n,m] = qe_n . qe_m is directly the exp2 exponent.
#define QSCALE 0.50500977f

// ---------------------------------------------------------------------------
// Kernel A (prep): 256 blocks x 1024 thr; block b owns n-slice n0=b*32.
// Emits qe slice, blocked vht slice, seeds out with x (pass2 atomic-adds),
// zeroes Ln (pass1 atomic-adds).
// vht[nblk][c][inner32]: inner pos = q*8 + h*4 + r for n_local = h*16+q*4+r;
// a lane's f16x8 at inner q*8 holds n_local {q*4..+3, 16+q*4..+3} = the two
// K=16 PV A-frags.
// ---------------------------------------------------------------------------
__global__ __launch_bounds__(1024) void prep_kernel(
    const float* __restrict__ x, const float* __restrict__ W,
    const float* __restrict__ bias, _Float16* __restrict__ qe,
    _Float16* __restrict__ vht, float* __restrict__ Ln,
    float* __restrict__ out) {
  __shared__ float Wl[32 * 65];
  __shared__ float xl[64 * 36];
  int t = threadIdx.x, b = blockIdx.x;
  int n0 = b * 32;
  if (b < 8) Ln[b * 1024 + t] = 0.f;  // zero the softmax-denominator accum
  for (int i = t; i < 2048; i += 1024) Wl[(i >> 6) * 65 + (i & 63)] = W[i];
  if (t < 512) {
    int c = t >> 3, j4 = t & 7;  // j4 = n_local/4
    f32x4 v = *(const f32x4*)(x + c * N_TOK + n0 + j4 * 4);
    *(f32x4*)&xl[c * 36 + j4 * 4] = v;
    *(f32x4*)(out + c * N_TOK + n0 + j4 * 4) = v;  // seed out = x
    f16x4 hv;
#pragma unroll
    for (int j = 0; j < 4; ++j) hv[j] = (_Float16)v[j];
    int q = j4 & 3, h = j4 >> 2;
    *(f16x4*)(vht + b * 2048 + c * 32 + q * 8 + h * 4) = hv;
  }
  __syncthreads();
  int nl = t >> 5, o = t & 31;
  float a0 = bias[o], a1 = 0.f;
#pragma unroll
  for (int c = 0; c < 32; ++c) {
    a0 = fmaf(Wl[o * 65 + c], xl[c * 36 + nl], a0);
    a1 = fmaf(Wl[o * 65 + 32 + c], xl[(32 + c) * 36 + nl], a1);
  }
  qe[(n0 + nl) * 32 + o] = (_Float16)((a0 + a1) * QSCALE);
}

// ---------------------------------------------------------------------------
// Kernel B (pass 1): Ln[n] += sum_{m in m-half} exp2(qe_n . qe_m)
// 256 blocks = 128 row-tiles (64 n each) x 2 m-halves. 16 waves split the
// 4096-m half 16 ways (256 m each). Per-block traffic ~0.26 MB (vs 0.5).
// Partial row-sums are exp-space additive -> unsafeAtomicAdd (2 operands
// per address, f32 add commutative => deterministic).
// ---------------------------------------------------------------------------
__global__ __launch_bounds__(1024) void pass1_kernel(
    const _Float16* __restrict__ qe, float* __restrict__ Ln) {
  __shared__ float Lp[16][64];
  int t = threadIdx.x, b = blockIdx.x;
  int w = t >> 6, lane = t & 63, quad = lane >> 4, l15 = lane & 15;
  int n0 = (b >> 1) * 64;
  int mbase = (b & 1) * 4096 + w * 256;
  f16x8 af[4];
#pragma unroll
  for (int g = 0; g < 4; ++g)
    af[g] = *(const f16x8*)(qe + (n0 + g * 16 + l15) * 32 + quad * 8);
  f32x4 sums[4];
#pragma unroll
  for (int g = 0; g < 4; ++g) sums[g] = f32x4{0.f, 0.f, 0.f, 0.f};
  for (int mt = 0; mt < 8; ++mt) {
    int m0 = mbase + mt * 32;
    f16x8 bf0 = *(const f16x8*)(qe + (m0 + l15) * 32 + quad * 8);
    f16x8 bf1 = *(const f16x8*)(qe + (m0 + 16 + l15) * 32 + quad * 8);
    f32x4 zero = {0.f, 0.f, 0.f, 0.f};
#pragma unroll
    for (int g = 0; g < 4; ++g) {
      f32x4 s0 = mfma_k32(af[g], bf0, zero);  // rows n0+g*16+quad*4+r
      f32x4 s1 = mfma_k32(af[g], bf1, zero);
#pragma unroll
      for (int r = 0; r < 4; ++r)
        sums[g][r] +=
            __builtin_amdgcn_exp2f(s0[r]) + __builtin_amdgcn_exp2f(s1[r]);
    }
  }
  // reduce across the 16 m-columns (l15 = lane bits 0..3)
#pragma unroll
  for (int g = 0; g < 4; ++g)
#pragma unroll
    for (int r = 0; r < 4; ++r)
#pragma unroll
      for (int mask = 1; mask < 16; mask <<= 1)
        sums[g][r] += __shfl_xor(sums[g][r], mask, 64);
  if (l15 == 0) {
#pragma unroll
    for (int g = 0; g < 4; ++g)
      *(f32x4*)&Lp[w][g * 16 + quad * 4] = sums[g];
  }
  __syncthreads();
  if (t < 64) {
    float L = 0.f;
#pragma unroll
    for (int ww = 0; ww < 16; ++ww) L += Lp[ww][t];
    unsafeAtomicAdd(Ln + n0 + t, L);
  }
}

// ---------------------------------------------------------------------------
// Kernel C (pass 2): out[c,m] += sum_{n in n-half} vh[c,n]*exp2(s_nm - Bn)
// 256 blocks = 128 m-tiles (64 m each!) x 2 n-halves -> per-block traffic
// 0.77 MB (vs 1.5), halving the per-CU L2 delivery that bounded round 3.
// 16 waves = 8 n-segs (512 n) x 2 c-halves (32 c). acc[2ct][4mt] = 32 VGPR.
// Bn = log2(Ln) computed inline per chunk. Zero LDS in main loop; P feeds
// PV in-register via K=16 MFMA. launch_bounds(1024,4): 128-VGPR budget
// (grid==CU count -> 1 block/CU anyway, costs nothing).
// ---------------------------------------------------------------------------
__global__ __launch_bounds__(1024, 4) void pass2_kernel(
    const _Float16* __restrict__ qe, const _Float16* __restrict__ vht,
    const float* __restrict__ Ln, float* __restrict__ out) {
  __shared__ float Ot[4 * 64 * 65];  // combine: [4 sets][64 c][65 m]
  int t = threadIdx.x, b = blockIdx.x;
  int w = t >> 6, lane = t & 63, quad = lane >> 4, l15 = lane & 15;
  int m0 = (b >> 1) * 64;    // 64-m tile
  int nh = b & 1;            // n-half (nh = b&1 -> each XCD sees ONE half)
  int chalf = w >> 3, nseg = w & 7;
  int nbase = nh * 4096 + nseg * 512;

  f16x8 bm[4];
#pragma unroll
  for (int mt = 0; mt < 4; ++mt)
    bm[mt] = *(const f16x8*)(qe + (m0 + mt * 16 + l15) * 32 + quad * 8);

  f32x4 acc[2][4];
#pragma unroll
  for (int ct = 0; ct < 2; ++ct)
#pragma unroll
    for (int mt = 0; mt < 4; ++mt) acc[ct][mt] = f32x4{0.f, 0.f, 0.f, 0.f};

  for (int ch = 0; ch < 16; ++ch) {
    int nb = nbase + ch * 32;
    f16x8 an0 = *(const f16x8*)(qe + (nb + l15) * 32 + quad * 8);
    f16x8 an1 = *(const f16x8*)(qe + (nb + 16 + l15) * 32 + quad * 8);
    f32x4 Lq0 = *(const f32x4*)(Ln + nb + quad * 4);
    f32x4 Lq1 = *(const f32x4*)(Ln + nb + 16 + quad * 4);
    const _Float16* vb =
        vht + (nb >> 5) * 2048 + (chalf * 32) * 32 + l15 * 32 + quad * 8;
    f16x8 av0 = *(const f16x8*)(vb);
    f16x8 av1 = *(const f16x8*)(vb + 512);  // +16 c rows
    f32x4 Bq0, Bq1;
#pragma unroll
    for (int r = 0; r < 4; ++r) {
      Bq0[r] = __builtin_amdgcn_logf(Lq0[r]);  // v_log_f32 = log2
      Bq1[r] = __builtin_amdgcn_logf(Lq1[r]);
    }
    f32x4 zero = {0.f, 0.f, 0.f, 0.f};
    f16x4 p0[4], p1[4];
#pragma unroll
    for (int mt = 0; mt < 4; ++mt) {
      f32x4 s0 = mfma_k32(an0, bm[mt], zero);  // n=nb+quad*4+r, m=mt*16+l15
      f32x4 s1 = mfma_k32(an1, bm[mt], zero);  // n=nb+16+quad*4+r
#pragma unroll
      for (int r = 0; r < 4; ++r) {
        p0[mt][r] = (_Float16)__builtin_amdgcn_exp2f(s0[r] - Bq0[r]);
        p1[mt][r] = (_Float16)__builtin_amdgcn_exp2f(s1[r] - Bq1[r]);
      }
    }
#pragma unroll
    for (int ct = 0; ct < 2; ++ct) {
      f16x8 av = (ct == 0) ? av0 : av1;
      f16x4 lo, hi;
#pragma unroll
      for (int j = 0; j < 4; ++j) {
        lo[j] = av[j];
        hi[j] = av[j + 4];
      }
#pragma unroll
      for (int mt = 0; mt < 4; ++mt) {
        acc[ct][mt] = mfma_k16(lo, p0[mt], acc[ct][mt]);
        acc[ct][mt] = mfma_k16(hi, p1[mt], acc[ct][mt]);
      }
    }
  }

  // Combine partials across 8 n-segments (8 -> 4 -> 1), then atomic out.
  if (nseg < 4) {
#pragma unroll
    for (int ct = 0; ct < 2; ++ct)
#pragma unroll
      for (int mt = 0; mt < 4; ++mt)
#pragma unroll
        for (int r = 0; r < 4; ++r)
          Ot[(nseg * 64 + chalf * 32 + ct * 16 + quad * 4 + r) * 65 +
             mt * 16 + l15] = acc[ct][mt][r];
  }
  __syncthreads();
  if (nseg >= 4) {
#pragma unroll
    for (int ct = 0; ct < 2; ++ct)
#pragma unroll
      for (int mt = 0; mt < 4; ++mt)
#pragma unroll
        for (int r = 0; r < 4; ++r)
          Ot[((nseg - 4) * 64 + chalf * 32 + ct * 16 + quad * 4 + r) * 65 +
             mt * 16 + l15] += acc[ct][mt][r];
  }
  __syncthreads();
  // 4096 outputs, 1024 threads -> 4 each; m consecutive across lanes.
  for (int idx = t; idx < 4096; idx += 1024) {
    int cc = idx >> 6, m = idx & 63;
    float v = 0.f;
#pragma unroll
    for (int s = 0; s < 4; ++s) v += Ot[(s * 64 + cc) * 65 + m];
    unsafeAtomicAdd(out + cc * N_TOK + m0 + m, v);
  }
}

// ---------------------------------------------------------------------------
extern "C" void kernel_launch(void* const* d_in, const int* in_sizes, int n_in,
                              void* d_out, int out_size, void* d_ws,
                              size_t ws_size, hipStream_t stream) {
  const float* x = (const float*)d_in[0];     // [64][8192]
  const float* W = (const float*)d_in[1];     // [32][64]
  const float* bias = (const float*)d_in[2];  // [32]
  float* out = (float*)d_out;                 // [64][8192]

  char* ws = (char*)d_ws;
  _Float16* qe = (_Float16*)ws;                 // 8192*32*2 = 512 KB
  _Float16* vht = (_Float16*)(ws + 524288);     // blocked vh: 1 MB
  float* Ln = (float*)(ws + 524288 + 1048576);  // 8192*4 = 32 KB

  prep_kernel<<<256, 1024, 0, stream>>>(x, W, bias, qe, vht, Ln, out);
  pass1_kernel<<<256, 1024, 0, stream>>>(qe, Ln);
  pass2_kernel<<<256, 1024, 0, stream>>>(qe, vht, Ln, out);
}